// Round 1
// baseline (37166.861 us; speedup 1.0000x reference)
//
#include <hip/hip_runtime.h>
#include <hip/hip_bf16.h>
#include <cstdint>

#define T_STEPS 1024
#define BATCH   128
#define DIM     256   // D
#define HID     256   // H
#define FF      128   // F

__device__ __forceinline__ float sigmoidf_(float x) {
    return 1.0f / (1.0f + __expf(-x));
}

__device__ __forceinline__ float tanhf_(float x) {
    // tanh(x) = 1 - 2/(e^{2x}+1); exact identity, robust at +/-inf
    float e = __expf(2.0f * x);
    return 1.0f - 2.0f / (e + 1.0f);
}

__global__ __launch_bounds__(512)
void qlstm_fp32_kernel(const float* __restrict__ x,
                       const float* __restrict__ Wg,
                       const float* __restrict__ bg,
                       const float* __restrict__ W1,
                       const float* __restrict__ b1,
                       const float* __restrict__ W2,
                       const float* __restrict__ b2,
                       float* __restrict__ out)
{
    const int b   = blockIdx.x;
    const int tid = threadIdx.x;

    __shared__ float comb[DIM + HID];   // [x(t) | h(t-1)]
    __shared__ float zbuf[4 * HID];     // gate pre-activations (1024)
    __shared__ float h1buf[4 * FF];     // FFN hidden (512)
    __shared__ float z2buf[4 * HID];    // FFN out (1024)
    __shared__ float cbuf[HID];         // cell state
    __shared__ float bgs[4 * HID];
    __shared__ float b1s[4 * FF];
    __shared__ float b2s[4 * HID];

    // preload biases, init state
    for (int i = tid; i < 4 * HID; i += 512) bgs[i] = bg[i];
    b1s[tid] = b1[tid];                        // 512 elements == blockDim
    for (int i = tid; i < 4 * HID; i += 512) b2s[i] = b2[i];
    if (tid < HID) { cbuf[tid] = 0.0f; comb[DIM + tid] = 0.0f; }

    const float2* __restrict__ wgv = reinterpret_cast<const float2*>(Wg);

    for (int t = 0; t < T_STEPS; ++t) {
        __syncthreads();   // prior-step update visible
        if (tid < DIM) comb[tid] = x[((size_t)t * BATCH + b) * DIM + tid];
        __syncthreads();

        // ---- phase 1: z = [x|h] @ Wg + bg ; thread -> cols (2*tid, 2*tid+1) ----
        float a0 = bgs[2 * tid], a1 = bgs[2 * tid + 1];
        {
            const float4* combv = reinterpret_cast<const float4*>(comb);
            #pragma unroll 4
            for (int k4 = 0; k4 < (DIM + HID) / 4; ++k4) {
                float4 cv = combv[k4];   // wave-uniform -> LDS broadcast
                float2 w0 = wgv[(4 * k4 + 0) * 512 + tid];
                float2 w1 = wgv[(4 * k4 + 1) * 512 + tid];
                float2 w2 = wgv[(4 * k4 + 2) * 512 + tid];
                float2 w3 = wgv[(4 * k4 + 3) * 512 + tid];
                a0 = fmaf(cv.x, w0.x, a0); a1 = fmaf(cv.x, w0.y, a1);
                a0 = fmaf(cv.y, w1.x, a0); a1 = fmaf(cv.y, w1.y, a1);
                a0 = fmaf(cv.z, w2.x, a0); a1 = fmaf(cv.z, w2.y, a1);
                a0 = fmaf(cv.w, w3.x, a0); a1 = fmaf(cv.w, w3.y, a1);
            }
        }
        zbuf[2 * tid] = a0;
        zbuf[2 * tid + 1] = a1;
        __syncthreads();

        // ---- phase 2: h1 = relu(z @ W1 + b1) ; thread -> (g = tid>>7, f = tid&127) ----
        {
            const int g = tid >> 7, f = tid & 127;
            const float* __restrict__ w1p = W1 + (size_t)g * HID * FF + f;
            const float4* zv = reinterpret_cast<const float4*>(zbuf + g * HID);
            float acc = b1s[tid];
            #pragma unroll 4
            for (int h4 = 0; h4 < HID / 4; ++h4) {
                float4 z4 = zv[h4];      // wave-uniform -> broadcast
                acc = fmaf(z4.x, w1p[(4 * h4 + 0) * FF], acc);
                acc = fmaf(z4.y, w1p[(4 * h4 + 1) * FF], acc);
                acc = fmaf(z4.z, w1p[(4 * h4 + 2) * FF], acc);
                acc = fmaf(z4.w, w1p[(4 * h4 + 3) * FF], acc);
            }
            h1buf[tid] = fmaxf(acc, 0.0f);
        }
        __syncthreads();

        // ---- phase 3: z2 = h1 @ W2 + b2 ; thread -> gates (g0, g0+1) at col h ----
        {
            const int h  = tid & 255;
            const int g0 = (tid >> 8) << 1;   // 0 or 2
            const float* __restrict__ w2a = W2 + (size_t)g0 * FF * HID + h;
            const float* __restrict__ w2b = w2a + FF * HID;
            const float4* h1va = reinterpret_cast<const float4*>(h1buf + g0 * FF);
            const float4* h1vb = reinterpret_cast<const float4*>(h1buf + (g0 + 1) * FF);
            float acc0 = b2s[g0 * HID + h];
            float acc1 = b2s[(g0 + 1) * HID + h];
            #pragma unroll 4
            for (int f4 = 0; f4 < FF / 4; ++f4) {
                float4 ha = h1va[f4], hb = h1vb[f4];   // broadcast
                acc0 = fmaf(ha.x, w2a[(4 * f4 + 0) * HID], acc0);
                acc0 = fmaf(ha.y, w2a[(4 * f4 + 1) * HID], acc0);
                acc0 = fmaf(ha.z, w2a[(4 * f4 + 2) * HID], acc0);
                acc0 = fmaf(ha.w, w2a[(4 * f4 + 3) * HID], acc0);
                acc1 = fmaf(hb.x, w2b[(4 * f4 + 0) * HID], acc1);
                acc1 = fmaf(hb.y, w2b[(4 * f4 + 1) * HID], acc1);
                acc1 = fmaf(hb.z, w2b[(4 * f4 + 2) * HID], acc1);
                acc1 = fmaf(hb.w, w2b[(4 * f4 + 3) * HID], acc1);
            }
            z2buf[g0 * HID + h] = acc0;
            z2buf[(g0 + 1) * HID + h] = acc1;
        }
        __syncthreads();

        // ---- gate update (threads 0..255) ----
        if (tid < HID) {
            float zf = z2buf[tid];
            float zi = z2buf[HID + tid];
            float zg = z2buf[2 * HID + tid];
            float zo = z2buf[3 * HID + tid];
            float fg = sigmoidf_(zf);
            float ig = sigmoidf_(zi);
            float gg = tanhf_(zg);
            float og = sigmoidf_(zo);
            float c  = fmaf(fg, cbuf[tid], ig * gg);
            float hh = og * tanhf_(c);
            cbuf[tid] = c;
            comb[DIM + tid] = hh;
            out[((size_t)t * BATCH + b) * HID + tid] = hh;
        }
    }

    __syncthreads();
    if (tid < HID) {
        out[(size_t)T_STEPS * BATCH * HID + (size_t)b * HID + tid] = comb[DIM + tid];
        out[(size_t)T_STEPS * BATCH * HID + (size_t)BATCH * HID + (size_t)b * HID + tid] = cbuf[tid];
    }
}

extern "C" void kernel_launch(void* const* d_in, const int* in_sizes, int n_in,
                              void* d_out, int out_size, void* d_ws, size_t ws_size,
                              hipStream_t stream) {
    const float* x  = (const float*)d_in[0];
    const float* Wg = (const float*)d_in[1];
    const float* bg = (const float*)d_in[2];
    const float* W1 = (const float*)d_in[3];
    const float* b1 = (const float*)d_in[4];
    const float* W2 = (const float*)d_in[5];
    const float* b2 = (const float*)d_in[6];
    float* out = (float*)d_out;

    qlstm_fp32_kernel<<<BATCH, 512, 0, stream>>>(x, Wg, bg, W1, b1, W2, b2, out);
}

// Round 2
// 12234.623 us; speedup vs baseline: 3.0378x; 3.0378x over previous
//
#include <hip/hip_runtime.h>
#include <hip/hip_fp16.h>
#include <cstdint>

#define T_STEPS 1024
#define BATCH   128
#define DIM     256   // D
#define HID     256   // H
#define FF      128   // F
#define KC      (DIM + HID)   // 512

// fp16 packed-weight layout in d_ws (units: __half):
//   WgP  at 0      : [KC/8][4H][8]   = 64*1024*8  = 524288 halfs (1 MB)
//   W1P  at 524288 : [4][H/8][F][8]  = 4*32*128*8 = 131072 halfs (256 KB)
//   W2P  at 655360 : [4][F/8][H][8]  = 4*16*256*8 = 131072 halfs (256 KB)
#define WGP_OFF 0
#define W1P_OFF 524288
#define W2P_OFF 655360
#define WS_HALFS 786432   // 1.5 MB

__device__ __forceinline__ float sigmoidf_(float x) {
    return 1.0f / (1.0f + __expf(-x));
}
__device__ __forceinline__ float tanhf_(float x) {
    float e = __expf(2.0f * x);
    return 1.0f - 2.0f / (e + 1.0f);
}

// ---------------- weight convert + repack (fp32 -> fp16, 16B-per-thread tiles) ----------
__global__ __launch_bounds__(256)
void convert_kernel(const float* __restrict__ Wg,
                    const float* __restrict__ W1,
                    const float* __restrict__ W2,
                    __half* __restrict__ ws)
{
    int i = blockIdx.x * 256 + threadIdx.x;
    if (i < 524288) {
        // Wg [KC][4H] flat: k = i>>10, c = i&1023 -> WgP[(k>>3)*1024 + c][k&7]
        int k = i >> 10, c = i & 1023;
        ws[WGP_OFF + (((size_t)(k >> 3) << 10) + c) * 8 + (k & 7)] = __float2half(Wg[i]);
    } else if (i < 655360) {
        int j = i - 524288;           // W1 [4][H][F]: g=j>>15, k=(j>>7)&255, f=j&127
        int g = j >> 15, k = (j >> 7) & 255, f = j & 127;
        ws[W1P_OFF + (((size_t)((g << 5) + (k >> 3)) << 7) + f) * 8 + (k & 7)] = __float2half(W1[j]);
    } else if (i < 786432) {
        int j = i - 655360;           // W2 [4][F][H]: g=j>>15, f=(j>>8)&127, h=j&255
        int g = j >> 15, f = (j >> 8) & 127, h = j & 255;
        ws[W2P_OFF + (((size_t)((g << 4) + (f >> 3)) << 8) + h) * 8 + (f & 7)] = __float2half(W2[j]);
    }
}

union H8 { uint4 u; __half h[8]; };

// ---------------- main recurrence: one WG per batch element, fp16 weights ----------------
__global__ __launch_bounds__(1024)
void qlstm_fp16w_kernel(const float* __restrict__ x,
                        const __half* __restrict__ ws,
                        const float* __restrict__ bg,
                        const float* __restrict__ b1,
                        const float* __restrict__ b2,
                        float* __restrict__ out)
{
    const int b   = blockIdx.x;
    const int tid = threadIdx.x;

    __shared__ float comb[KC];        // [x(t) | h(t-1)]
    __shared__ float zbuf[4 * HID];
    __shared__ float h1buf[4 * FF];
    __shared__ float z2buf[4 * HID];
    __shared__ float cbuf[HID];
    __shared__ float bgs[4 * HID];
    __shared__ float b1s[4 * FF];
    __shared__ float b2s[4 * HID];

    bgs[tid] = bg[tid];
    if (tid < 4 * FF) b1s[tid] = b1[tid];
    b2s[tid] = b2[tid];
    if (tid < HID) { cbuf[tid] = 0.0f; comb[DIM + tid] = 0.0f; }

    const uint4* __restrict__ wgp = reinterpret_cast<const uint4*>(ws + WGP_OFF);
    const uint4* __restrict__ w1p = reinterpret_cast<const uint4*>(ws + W1P_OFF);
    const uint4* __restrict__ w2p = reinterpret_cast<const uint4*>(ws + W2P_OFF);

    for (int t = 0; t < T_STEPS; ++t) {
        __syncthreads();                                     // gate update visible
        if (tid < DIM) comb[tid] = x[((size_t)t * BATCH + b) * DIM + tid];
        __syncthreads();

        // ---- phase 1: z[c] = sum_k comb[k] * Wg[k][c] + bg[c]; c = tid ----
        {
            const float4* combv = reinterpret_cast<const float4*>(comb);
            float acc = bgs[tid];
            #pragma unroll 8
            for (int k8 = 0; k8 < KC / 8; ++k8) {
                H8 w; w.u = wgp[(k8 << 10) + tid];
                float4 c0 = combv[2 * k8];
                float4 c1 = combv[2 * k8 + 1];
                acc = fmaf(c0.x, __half2float(w.h[0]), acc);
                acc = fmaf(c0.y, __half2float(w.h[1]), acc);
                acc = fmaf(c0.z, __half2float(w.h[2]), acc);
                acc = fmaf(c0.w, __half2float(w.h[3]), acc);
                acc = fmaf(c1.x, __half2float(w.h[4]), acc);
                acc = fmaf(c1.y, __half2float(w.h[5]), acc);
                acc = fmaf(c1.z, __half2float(w.h[6]), acc);
                acc = fmaf(c1.w, __half2float(w.h[7]), acc);
            }
            zbuf[tid] = acc;
        }
        __syncthreads();

        // ---- phase 2: h1[g][f] = relu(sum_k z[g][k] * W1[g][k][f] + b1); tid<512 ----
        if (tid < 4 * FF) {
            const int g = tid >> 7, f = tid & 127;
            const float4* zv = reinterpret_cast<const float4*>(zbuf + g * HID);
            float acc = b1s[tid];
            #pragma unroll 8
            for (int k8 = 0; k8 < HID / 8; ++k8) {
                H8 w; w.u = w1p[(((g << 5) + k8) << 7) + f];
                float4 z0 = zv[2 * k8];
                float4 z1 = zv[2 * k8 + 1];
                acc = fmaf(z0.x, __half2float(w.h[0]), acc);
                acc = fmaf(z0.y, __half2float(w.h[1]), acc);
                acc = fmaf(z0.z, __half2float(w.h[2]), acc);
                acc = fmaf(z0.w, __half2float(w.h[3]), acc);
                acc = fmaf(z1.x, __half2float(w.h[4]), acc);
                acc = fmaf(z1.y, __half2float(w.h[5]), acc);
                acc = fmaf(z1.z, __half2float(w.h[6]), acc);
                acc = fmaf(z1.w, __half2float(w.h[7]), acc);
            }
            h1buf[tid] = fmaxf(acc, 0.0f);
        }
        __syncthreads();

        // ---- phase 3: z2[g][h] = sum_f h1[g][f] * W2[g][f][h] + b2 ----
        {
            const int g = tid >> 8, h = tid & 255;
            const float4* hv = reinterpret_cast<const float4*>(h1buf + g * FF);
            float acc = b2s[tid];
            #pragma unroll 8
            for (int f8 = 0; f8 < FF / 8; ++f8) {
                H8 w; w.u = w2p[(((g << 4) + f8) << 8) + h];
                float4 h0 = hv[2 * f8];
                float4 h1 = hv[2 * f8 + 1];
                acc = fmaf(h0.x, __half2float(w.h[0]), acc);
                acc = fmaf(h0.y, __half2float(w.h[1]), acc);
                acc = fmaf(h0.z, __half2float(w.h[2]), acc);
                acc = fmaf(h0.w, __half2float(w.h[3]), acc);
                acc = fmaf(h1.x, __half2float(w.h[4]), acc);
                acc = fmaf(h1.y, __half2float(w.h[5]), acc);
                acc = fmaf(h1.z, __half2float(w.h[6]), acc);
                acc = fmaf(h1.w, __half2float(w.h[7]), acc);
            }
            z2buf[tid] = acc;
        }
        __syncthreads();

        // ---- gate update (threads 0..255) ----
        if (tid < HID) {
            float zf = z2buf[tid];
            float zi = z2buf[HID + tid];
            float zg = z2buf[2 * HID + tid];
            float zo = z2buf[3 * HID + tid];
            float fg = sigmoidf_(zf);
            float ig = sigmoidf_(zi);
            float gg = tanhf_(zg);
            float og = sigmoidf_(zo);
            float c  = fmaf(fg, cbuf[tid], ig * gg);
            float hh = og * tanhf_(c);
            cbuf[tid] = c;
            comb[DIM + tid] = hh;
            out[((size_t)t * BATCH + b) * HID + tid] = hh;
        }
    }

    __syncthreads();
    if (tid < HID) {
        out[(size_t)T_STEPS * BATCH * HID + (size_t)b * HID + tid] = comb[DIM + tid];
        out[(size_t)T_STEPS * BATCH * HID + (size_t)BATCH * HID + (size_t)b * HID + tid] = cbuf[tid];
    }
}

// ---------------- fp32 fallback (round-1 kernel) if ws is too small ----------------
__global__ __launch_bounds__(512)
void qlstm_fp32_kernel(const float* __restrict__ x,
                       const float* __restrict__ Wg,
                       const float* __restrict__ bg,
                       const float* __restrict__ W1,
                       const float* __restrict__ b1,
                       const float* __restrict__ W2,
                       const float* __restrict__ b2,
                       float* __restrict__ out)
{
    const int b   = blockIdx.x;
    const int tid = threadIdx.x;

    __shared__ float comb[DIM + HID];
    __shared__ float zbuf[4 * HID];
    __shared__ float h1buf[4 * FF];
    __shared__ float z2buf[4 * HID];
    __shared__ float cbuf[HID];
    __shared__ float bgs[4 * HID];
    __shared__ float b1s[4 * FF];
    __shared__ float b2s[4 * HID];

    for (int i = tid; i < 4 * HID; i += 512) bgs[i] = bg[i];
    b1s[tid] = b1[tid];
    for (int i = tid; i < 4 * HID; i += 512) b2s[i] = b2[i];
    if (tid < HID) { cbuf[tid] = 0.0f; comb[DIM + tid] = 0.0f; }

    const float2* __restrict__ wgv = reinterpret_cast<const float2*>(Wg);

    for (int t = 0; t < T_STEPS; ++t) {
        __syncthreads();
        if (tid < DIM) comb[tid] = x[((size_t)t * BATCH + b) * DIM + tid];
        __syncthreads();

        float a0 = bgs[2 * tid], a1 = bgs[2 * tid + 1];
        {
            const float4* combv = reinterpret_cast<const float4*>(comb);
            #pragma unroll 4
            for (int k4 = 0; k4 < (DIM + HID) / 4; ++k4) {
                float4 cv = combv[k4];
                float2 w0 = wgv[(4 * k4 + 0) * 512 + tid];
                float2 w1 = wgv[(4 * k4 + 1) * 512 + tid];
                float2 w2 = wgv[(4 * k4 + 2) * 512 + tid];
                float2 w3 = wgv[(4 * k4 + 3) * 512 + tid];
                a0 = fmaf(cv.x, w0.x, a0); a1 = fmaf(cv.x, w0.y, a1);
                a0 = fmaf(cv.y, w1.x, a0); a1 = fmaf(cv.y, w1.y, a1);
                a0 = fmaf(cv.z, w2.x, a0); a1 = fmaf(cv.z, w2.y, a1);
                a0 = fmaf(cv.w, w3.x, a0); a1 = fmaf(cv.w, w3.y, a1);
            }
        }
        zbuf[2 * tid] = a0;
        zbuf[2 * tid + 1] = a1;
        __syncthreads();

        {
            const int g = tid >> 7, f = tid & 127;
            const float* __restrict__ w1q = W1 + (size_t)g * HID * FF + f;
            const float4* zv = reinterpret_cast<const float4*>(zbuf + g * HID);
            float acc = b1s[tid];
            #pragma unroll 4
            for (int h4 = 0; h4 < HID / 4; ++h4) {
                float4 z4 = zv[h4];
                acc = fmaf(z4.x, w1q[(4 * h4 + 0) * FF], acc);
                acc = fmaf(z4.y, w1q[(4 * h4 + 1) * FF], acc);
                acc = fmaf(z4.z, w1q[(4 * h4 + 2) * FF], acc);
                acc = fmaf(z4.w, w1q[(4 * h4 + 3) * FF], acc);
            }
            h1buf[tid] = fmaxf(acc, 0.0f);
        }
        __syncthreads();

        {
            const int h  = tid & 255;
            const int g0 = (tid >> 8) << 1;
            const float* __restrict__ w2a = W2 + (size_t)g0 * FF * HID + h;
            const float* __restrict__ w2b = w2a + FF * HID;
            const float4* h1va = reinterpret_cast<const float4*>(h1buf + g0 * FF);
            const float4* h1vb = reinterpret_cast<const float4*>(h1buf + (g0 + 1) * FF);
            float acc0 = b2s[g0 * HID + h];
            float acc1 = b2s[(g0 + 1) * HID + h];
            #pragma unroll 4
            for (int f4 = 0; f4 < FF / 4; ++f4) {
                float4 ha = h1va[f4], hb = h1vb[f4];
                acc0 = fmaf(ha.x, w2a[(4 * f4 + 0) * HID], acc0);
                acc0 = fmaf(ha.y, w2a[(4 * f4 + 1) * HID], acc0);
                acc0 = fmaf(ha.z, w2a[(4 * f4 + 2) * HID], acc0);
                acc0 = fmaf(ha.w, w2a[(4 * f4 + 3) * HID], acc0);
                acc1 = fmaf(hb.x, w2b[(4 * f4 + 0) * HID], acc1);
                acc1 = fmaf(hb.y, w2b[(4 * f4 + 1) * HID], acc1);
                acc1 = fmaf(hb.z, w2b[(4 * f4 + 2) * HID], acc1);
                acc1 = fmaf(hb.w, w2b[(4 * f4 + 3) * HID], acc1);
            }
            z2buf[g0 * HID + h] = acc0;
            z2buf[(g0 + 1) * HID + h] = acc1;
        }
        __syncthreads();

        if (tid < HID) {
            float zf = z2buf[tid];
            float zi = z2buf[HID + tid];
            float zg = z2buf[2 * HID + tid];
            float zo = z2buf[3 * HID + tid];
            float fg = sigmoidf_(zf);
            float ig = sigmoidf_(zi);
            float gg = tanhf_(zg);
            float og = sigmoidf_(zo);
            float c  = fmaf(fg, cbuf[tid], ig * gg);
            float hh = og * tanhf_(c);
            cbuf[tid] = c;
            comb[DIM + tid] = hh;
            out[((size_t)t * BATCH + b) * HID + tid] = hh;
        }
    }

    __syncthreads();
    if (tid < HID) {
        out[(size_t)T_STEPS * BATCH * HID + (size_t)b * HID + tid] = comb[DIM + tid];
        out[(size_t)T_STEPS * BATCH * HID + (size_t)BATCH * HID + (size_t)b * HID + tid] = cbuf[tid];
    }
}

extern "C" void kernel_launch(void* const* d_in, const int* in_sizes, int n_in,
                              void* d_out, int out_size, void* d_ws, size_t ws_size,
                              hipStream_t stream) {
    const float* x  = (const float*)d_in[0];
    const float* Wg = (const float*)d_in[1];
    const float* bg = (const float*)d_in[2];
    const float* W1 = (const float*)d_in[3];
    const float* b1 = (const float*)d_in[4];
    const float* W2 = (const float*)d_in[5];
    const float* b2 = (const float*)d_in[6];
    float* out = (float*)d_out;

    if (ws_size >= (size_t)WS_HALFS * sizeof(__half)) {
        __half* ws = (__half*)d_ws;
        convert_kernel<<<WS_HALFS / 256, 256, 0, stream>>>(Wg, W1, W2, ws);
        qlstm_fp16w_kernel<<<BATCH, 1024, 0, stream>>>(x, ws, bg, b1, b2, out);
    } else {
        qlstm_fp32_kernel<<<BATCH, 512, 0, stream>>>(x, Wg, bg, W1, b1, W2, b2, out);
    }
}